// Round 3
// baseline (1206.343 us; speedup 1.0000x reference)
//
#include <hip/hip_runtime.h>
#include <hip/hip_bf16.h>
#include <stdint.h>

// Problem constants: [T,B,D]=[4096,4,1024], H=4096. f32 inputs, f32 outputs.
// Outputs: soft [B,T] f32 at out[0..16384), hard [B,T] f32 at out[16384..32768).
#define T_STEPS 4096
#define BATCH   4
#define D_IN    1024
#define H_DIM   4096
#define M_ROWS  (T_STEPS * BATCH)

typedef __attribute__((ext_vector_type(8)))  short bf16x8;
typedef __attribute__((ext_vector_type(4)))  float f32x4;
typedef __attribute__((ext_vector_type(16))) float f32x16;

__device__ __forceinline__ float b2f(unsigned short u) {
    union { unsigned int i; float f; } x; x.i = ((unsigned int)u) << 16; return x.f;
}
__device__ __forceinline__ unsigned short f2bf_rne(float f) {
    union { float f; unsigned int u; } v; v.f = f;
    return (unsigned short)((v.u + 0x7FFFu + ((v.u >> 16) & 1u)) >> 16);
}

__device__ __forceinline__ void load_lds16(const unsigned short* g, unsigned short* l) {
    __builtin_amdgcn_global_load_lds(
        (const __attribute__((address_space(1))) void*)g,
        (__attribute__((address_space(3))) void*)l, 16, 0, 0);
}

// ---------------- prep: split X (fat blocks) + split/transpose W + zero logits ----------------
// blocks [0,4096): split_x (4 float4/thread) | [4096,6144): split_w | [6144,6176): zero logits
__global__ void __launch_bounds__(256)
prep(const float* __restrict__ hidden,
     const float* __restrict__ Wb1, const float* __restrict__ Wr1,
     unsigned short* __restrict__ Xhi, unsigned short* __restrict__ Xlo,
     unsigned short* __restrict__ WThi, unsigned short* __restrict__ WTlo,
     float* __restrict__ logits)
{
    __shared__ float tile[64][65];
    const int bid = blockIdx.x;
    const int t = threadIdx.x;

    if (bid < 4096) {
        // split hidden f32 -> (hi, lo) bf16, same layout; 4 coalesced float4 per thread
#pragma unroll
        for (int j = 0; j < 4; ++j) {
            int i = bid * 1024 + j * 256 + t;
            float4 x = ((const float4*)hidden)[i];
            ushort4 h, l;
            h.x = f2bf_rne(x.x); l.x = f2bf_rne(x.x - b2f(h.x));
            h.y = f2bf_rne(x.y); l.y = f2bf_rne(x.y - b2f(h.y));
            h.z = f2bf_rne(x.z); l.z = f2bf_rne(x.z - b2f(h.z));
            h.w = f2bf_rne(x.w); l.w = f2bf_rne(x.w - b2f(h.w));
            ((ushort4*)Xhi)[i] = h;
            ((ushort4*)Xlo)[i] = l;
        }
    } else if (bid < 6144) {
        // transpose+split W [D][H] -> WT [H][D] for both matrices
        int wb  = bid - 4096;
        int z   = wb >> 10;                   // 0=boundary, 1=reset
        int rem = wb & 1023;
        int bx  = (rem & 63) * 64;            // H direction
        int by  = (rem >> 6) * 64;            // D direction
        const float* src = z ? Wr1 : Wb1;
        const size_t moff = (size_t)z * H_DIM * D_IN;
        const int c4 = (t & 15) * 4;
        const int r0 = (t >> 4) * 4;
#pragma unroll
        for (int rr = 0; rr < 4; ++rr) {
            int r = r0 + rr;
            float4 v = *(const float4*)(src + (size_t)(by + r) * H_DIM + bx + c4);
            tile[r][c4 + 0] = v.x; tile[r][c4 + 1] = v.y;
            tile[r][c4 + 2] = v.z; tile[r][c4 + 3] = v.w;
        }
        __syncthreads();
#pragma unroll
        for (int rr = 0; rr < 4; ++rr) {
            int c = r0 + rr;
            ushort4 h, l;
            float f0 = tile[c4 + 0][c], f1 = tile[c4 + 1][c];
            float f2 = tile[c4 + 2][c], f3 = tile[c4 + 3][c];
            h.x = f2bf_rne(f0); l.x = f2bf_rne(f0 - b2f(h.x));
            h.y = f2bf_rne(f1); l.y = f2bf_rne(f1 - b2f(h.y));
            h.z = f2bf_rne(f2); l.z = f2bf_rne(f2 - b2f(h.z));
            h.w = f2bf_rne(f3); l.w = f2bf_rne(f3 - b2f(h.w));
            size_t o = moff + (size_t)(bx + c) * D_IN + by + c4;
            *(ushort4*)(WThi + o) = h;
            *(ushort4*)(WTlo + o) = l;
        }
    } else {
#pragma unroll
        for (int j = 0; j < 4; ++j)
            logits[(bid - 6144) * 1024 + j * 256 + t] = 0.f;   // 32 blocks x 1024 = 32768
    }
}

// ------------- fused split-f32 GEMM + relu + (.)@W2 reduction -------------
// Round-0 regime restored (2 blocks/CU, 4 waves, 64x128 wave tile, 48 KB LDS, 256 thr)
// + two same-regime levers:
//  * 32x32x16 bf16 MFMA (pipe rate 2495 vs 2176 TF; same FLOP in 13% less pipe time)
//  * double-buffer at BK=16 (2 x 24 KB = 48 KB total -> still 2 blocks/CU):
//    STAGE(next chunk -> other buffer) before COMPUTE(current); 1 barrier/chunk.
// BK=16 rows are 32 B: a wave's fragment read (row=lane&31, 16B half=(lane>>5)) is a
// CONTIGUOUS 2 KB block -> bank-balanced with no swizzle; global_load_lds dest is the
// same linear layout, so staging needs no swizzle either.
// acc = 2x4 f32x16 = 128 regs; __launch_bounds__(256,2) -> 2 waves/SIMD as round 0.
__global__ void __launch_bounds__(256, 2)
gemm_fused3(const unsigned short* __restrict__ Xhi, const unsigned short* __restrict__ Xlo,
            const unsigned short* __restrict__ WThi, const unsigned short* __restrict__ WTlo,
            const float* __restrict__ b1b, const float* __restrict__ b1r,
            const float* __restrict__ w2b, const float* __restrict__ w2r,
            float* __restrict__ logits)              // [2][B][T] f32, atomically accumulated
{
    // per-buffer layout (ushort offsets), rows of 16 ushorts (=BK):
    // Ahi [0,2048) | Alo [2048,4096) | Bhi [4096,8192) | Blo [8192,12288). 24 KB each.
    __shared__ __align__(16) unsigned short S0[12288];
    __shared__ __align__(16) unsigned short S1[12288];

    const int t    = threadIdx.x;
    const int wave = t >> 6;
    const int lane = t & 63;
    const int l31  = lane & 31;
    const int h8   = (lane >> 5) * 8;        // k-half within BK=16
    const int wm   = (wave & 1) * 64;        // wave tile 64m x 128n
    const int wn   = (wave >> 1) * 128;

    const int mat = blockIdx.z;
    const int n0  = blockIdx.x * 256;
    const int m0  = blockIdx.y * 128;

    const size_t aoff = (size_t)m0 * D_IN;
    const size_t boff = (size_t)mat * H_DIM * D_IN + (size_t)n0 * D_IN;
    const unsigned short* Ah = Xhi + aoff;
    const unsigned short* Al = Xlo + aoff;
    const unsigned short* Bh = WThi + boff;
    const unsigned short* Bl = WTlo + boff;
    const float* b1 = mat ? b1r : b1b;
    const float* w2 = mat ? w2r : w2b;
    float* out = logits + mat * M_ROWS;

    // staging (BK=16, 256 threads): thread t covers row t>>1, 16B half t&1.
    // LDS dest = t*16B linear (global_load_lds requirement) == row*32B + half*16B,
    // exactly the fragment-read layout.
    const size_t gA  = (size_t)(t >> 1) * D_IN + (size_t)(t & 1) * 8;
    const size_t gB1 = gA + (size_t)128 * D_IN;       // B rows [128,256)
    const int tt8 = t * 8;                            // ushort offset = t*16B

#define STAGE(S, c)                                                           \
    do {                                                                      \
        const size_t k0_ = (size_t)(c) * 16;                                  \
        load_lds16(Ah + gA  + k0_, (S) + tt8);                                \
        load_lds16(Al + gA  + k0_, (S) + 2048 + tt8);                         \
        load_lds16(Bh + gA  + k0_, (S) + 4096 + tt8);                         \
        load_lds16(Bh + gB1 + k0_, (S) + 6144 + tt8);                         \
        load_lds16(Bl + gA  + k0_, (S) + 8192 + tt8);                         \
        load_lds16(Bl + gB1 + k0_, (S) + 10240 + tt8);                        \
    } while (0)

    // fragment read offsets (loop-invariant): A row = wm+i*32+l31, B row = wn+j*32+l31,
    // each lane reads its 16B k-half; contiguous 2KB per fragment -> conflict-free.
    int afo[2], bfo[4];
#pragma unroll
    for (int i = 0; i < 2; ++i) afo[i] = (wm + i * 32 + l31) * 16 + h8;
#pragma unroll
    for (int j = 0; j < 4; ++j) bfo[j] = (wn + j * 32 + l31) * 16 + h8;

    f32x16 acc[2][4] = {};

#define COMPUTE(S)                                                            \
    do {                                                                      \
        bf16x8 ah_[2], al_[2], bh_[4], bl_[4];                                \
        _Pragma("unroll") for (int i = 0; i < 2; ++i) {                       \
            ah_[i] = *(const bf16x8*)((S) + afo[i]);                          \
            al_[i] = *(const bf16x8*)((S) + 2048 + afo[i]);                   \
        }                                                                     \
        _Pragma("unroll") for (int j = 0; j < 4; ++j) {                       \
            bh_[j] = *(const bf16x8*)((S) + 4096 + bfo[j]);                   \
            bl_[j] = *(const bf16x8*)((S) + 8192 + bfo[j]);                   \
        }                                                                     \
        _Pragma("unroll") for (int i = 0; i < 2; ++i)                         \
        _Pragma("unroll") for (int j = 0; j < 4; ++j)                         \
            acc[i][j] = __builtin_amdgcn_mfma_f32_32x32x16_bf16(ah_[i], bh_[j], acc[i][j], 0, 0, 0); \
        _Pragma("unroll") for (int i = 0; i < 2; ++i)                         \
        _Pragma("unroll") for (int j = 0; j < 4; ++j)                         \
            acc[i][j] = __builtin_amdgcn_mfma_f32_32x32x16_bf16(al_[i], bh_[j], acc[i][j], 0, 0, 0); \
        _Pragma("unroll") for (int i = 0; i < 2; ++i)                         \
        _Pragma("unroll") for (int j = 0; j < 4; ++j)                         \
            acc[i][j] = __builtin_amdgcn_mfma_f32_32x32x16_bf16(ah_[i], bl_[j], acc[i][j], 0, 0, 0); \
    } while (0)

    STAGE(S0, 0);
    __syncthreads();                          // prologue drain (auto vmcnt(0))

#pragma unroll 1
    for (int c = 0; c < D_IN / 16; c += 2) {
        STAGE(S1, c + 1);                     // prefetch next chunk into other buffer
        COMPUTE(S0);                          // 24 MFMA cover the stage latency
        __syncthreads();                      // auto vmcnt(0): S1 ready, S0 reads done
        if (c + 2 < D_IN / 16) STAGE(S0, c + 2);
        COMPUTE(S1);
        __syncthreads();
    }

    // epilogue: relu(C + b1)*w2, reduce over this tile's n, accumulate to logits.
    // 32x32 C/D layout: col = lane&31, row = (reg&3) + 8*(reg>>2) + 4*(lane>>5).
    float b1v[4], w2v[4];
#pragma unroll
    for (int j = 0; j < 4; ++j) {
        int n = n0 + wn + j * 32 + l31;
        b1v[j] = b1[n];
        w2v[j] = w2[n];
    }
#pragma unroll
    for (int i = 0; i < 2; ++i) {
#pragma unroll
        for (int r = 0; r < 16; ++r) {
            float s = 0.f;
#pragma unroll
            for (int j = 0; j < 4; ++j) {
                float h = acc[i][j][r] + b1v[j];
                s += fmaxf(h, 0.f) * w2v[j];
            }
            s += __shfl_xor(s, 1, 64);
            s += __shfl_xor(s, 2, 64);
            s += __shfl_xor(s, 4, 64);
            s += __shfl_xor(s, 8, 64);
            s += __shfl_xor(s, 16, 64);
            if (l31 == 0) {
                int m = m0 + wm + i * 32 + (r & 3) + 8 * (r >> 2) + 4 * (lane >> 5);
                atomicAdd(&out[(m & (BATCH - 1)) * T_STEPS + (m >> 2)], s);  // -> [b][t]
            }
        }
    }
#undef STAGE
#undef COMPUTE
}

// ------------- finish: soft output (blocks 0..63) + serial LIF scan (block 64) -------------
// Scan is a 4096-step serial chain; loads are L2-latency-bound if issued in-chain.
// Fix: 16-step register prefetch ring (load chunk c+1 before processing chunk c;
// ~250 cyc of chain work hides the ~200 cyc L2 latency). x+bb2 / rl>0 computed off-chain.
__global__ void __launch_bounds__(256)
finish(const float* __restrict__ logits,
       const float* __restrict__ bb2p, const float* __restrict__ br2p,
       float* __restrict__ out)
{
    if (blockIdx.x < 64) {
        int i = blockIdx.x * 256 + threadIdx.x;
        out[i] = logits[i] + bb2p[0];                // soft = boundary logits [b][t] + bb2
        return;
    }
    int b = threadIdx.x;
    if (b >= BATCH) return;
    const float bb2 = bb2p[0];
    const float br2 = br2p[0];
    const float* xb = logits + b * T_STEPS;          // boundary logits, [b][t]
    const float* xr = logits + M_ROWS + b * T_STEPS; // reset logits
    float* hb = out + M_ROWS + b * T_STEPS;

    float4 cx[4], cr[4], nx[4] = {}, nr[4] = {};
#pragma unroll
    for (int q = 0; q < 4; ++q) {
        cx[q] = *(const float4*)(xb + q * 4);
        cr[q] = *(const float4*)(xr + q * 4);
    }

    float v = 0.f;
    for (int t0 = 0; t0 < T_STEPS; t0 += 16) {
        if (t0 + 16 < T_STEPS) {
#pragma unroll
            for (int q = 0; q < 4; ++q) {
                nx[q] = *(const float4*)(xb + t0 + 16 + q * 4);
                nr[q] = *(const float4*)(xr + t0 + 16 + q * 4);
            }
        }
#pragma unroll
        for (int q = 0; q < 4; ++q) {
            // off-chain precompute (same ops as before, just hoisted)
            float xs[4] = { cx[q].x + bb2, cx[q].y + bb2, cx[q].z + bb2, cx[q].w + bb2 };
            bool  rm[4] = { cr[q].x + br2 > 0.f, cr[q].y + br2 > 0.f,
                            cr[q].z + br2 > 0.f, cr[q].w + br2 > 0.f };
            float4 sv;
#pragma unroll
            for (int u = 0; u < 4; ++u) {
                v = v + (xs[u] - v) * 0.5f;          // bit-identical to reference step
                bool spike = (v >= 1.0f);
                ((float*)&sv)[u] = spike ? 1.0f : 0.0f;
                v = (spike || rm[u]) ? 0.f : v;
            }
            *(float4*)(hb + t0 + q * 4) = sv;
        }
#pragma unroll
        for (int q = 0; q < 4; ++q) { cx[q] = nx[q]; cr[q] = nr[q]; }
    }
}

extern "C" void kernel_launch(void* const* d_in, const int* in_sizes, int n_in,
                              void* d_out, int out_size, void* d_ws, size_t ws_size,
                              hipStream_t stream) {
    // dict order (confirmed): hidden, Wb1, bb1, Wb2, bb2, Wr1, br1, Wr2, br2
    const float* hidden = (const float*)d_in[0];   // [T,B,D] f32
    const float* Wb1    = (const float*)d_in[1];   // [D,H]
    const float* bb1    = (const float*)d_in[2];   // [H]
    const float* Wb2    = (const float*)d_in[3];   // [H,1]
    const float* bb2    = (const float*)d_in[4];   // [1]
    const float* Wr1    = (const float*)d_in[5];
    const float* br1    = (const float*)d_in[6];
    const float* Wr2    = (const float*)d_in[7];
    const float* br2    = (const float*)d_in[8];
    float* out = (float*)d_out;                    // f32: [soft B*T][hard B*T]

    // ws layout (96.13 MB): Xhi 32MB | Xlo 32MB | WThi 16MB | WTlo 16MB | logits 128KB
    unsigned short* Xhi  = (unsigned short*)d_ws;
    unsigned short* Xlo  = Xhi  + (size_t)M_ROWS * D_IN;
    unsigned short* WThi = Xlo  + (size_t)M_ROWS * D_IN;
    unsigned short* WTlo = WThi + (size_t)2 * H_DIM * D_IN;
    float* logits = (float*)(WTlo + (size_t)2 * H_DIM * D_IN);

    prep<<<dim3(6176), 256, 0, stream>>>(hidden, Wb1, Wr1, Xhi, Xlo, WThi, WTlo, logits);
    gemm_fused3<<<dim3(H_DIM / 256, M_ROWS / 128, 2), 256, 0, stream>>>(
        Xhi, Xlo, WThi, WTlo, bb1, br1, Wb2, Wr2, logits);
    finish<<<dim3(65), 256, 0, stream>>>(logits, bb2, br2, out);
}

// Round 4
// 1068.943 us; speedup vs baseline: 1.1285x; 1.1285x over previous
//
#include <hip/hip_runtime.h>
#include <hip/hip_bf16.h>
#include <stdint.h>

// Problem constants: [T,B,D]=[4096,4,1024], H=4096. f32 inputs, f32 outputs.
// Outputs: soft [B,T] f32 at out[0..16384), hard [B,T] f32 at out[16384..32768).
#define T_STEPS 4096
#define BATCH   4
#define D_IN    1024
#define H_DIM   4096
#define M_ROWS  (T_STEPS * BATCH)

typedef __attribute__((ext_vector_type(8)))  short bf16x8;
typedef __attribute__((ext_vector_type(4)))  float f32x4;
typedef __attribute__((ext_vector_type(16))) float f32x16;

__device__ __forceinline__ float b2f(unsigned short u) {
    union { unsigned int i; float f; } x; x.i = ((unsigned int)u) << 16; return x.f;
}
__device__ __forceinline__ unsigned short f2bf_rne(float f) {
    union { float f; unsigned int u; } v; v.f = f;
    return (unsigned short)((v.u + 0x7FFFu + ((v.u >> 16) & 1u)) >> 16);
}

__device__ __forceinline__ void load_lds16(const unsigned short* g, unsigned short* l) {
    __builtin_amdgcn_global_load_lds(
        (const __attribute__((address_space(1))) void*)g,
        (__attribute__((address_space(3))) void*)l, 16, 0, 0);
}

// ---------------- prep: split X (fat blocks) + split/transpose W + zero logits ----------------
// blocks [0,4096): split_x (4 float4/thread) | [4096,6144): split_w | [6144,6176): zero logits
__global__ void __launch_bounds__(256)
prep(const float* __restrict__ hidden,
     const float* __restrict__ Wb1, const float* __restrict__ Wr1,
     unsigned short* __restrict__ Xhi, unsigned short* __restrict__ Xlo,
     unsigned short* __restrict__ WThi, unsigned short* __restrict__ WTlo,
     float* __restrict__ logits)
{
    __shared__ float tile[64][65];
    const int bid = blockIdx.x;
    const int t = threadIdx.x;

    if (bid < 4096) {
        // split hidden f32 -> (hi, lo) bf16, same layout; 4 coalesced float4 per thread
#pragma unroll
        for (int j = 0; j < 4; ++j) {
            int i = bid * 1024 + j * 256 + t;
            float4 x = ((const float4*)hidden)[i];
            ushort4 h, l;
            h.x = f2bf_rne(x.x); l.x = f2bf_rne(x.x - b2f(h.x));
            h.y = f2bf_rne(x.y); l.y = f2bf_rne(x.y - b2f(h.y));
            h.z = f2bf_rne(x.z); l.z = f2bf_rne(x.z - b2f(h.z));
            h.w = f2bf_rne(x.w); l.w = f2bf_rne(x.w - b2f(h.w));
            ((ushort4*)Xhi)[i] = h;
            ((ushort4*)Xlo)[i] = l;
        }
    } else if (bid < 6144) {
        // transpose+split W [D][H] -> WT [H][D] for both matrices
        int wb  = bid - 4096;
        int z   = wb >> 10;                   // 0=boundary, 1=reset
        int rem = wb & 1023;
        int bx  = (rem & 63) * 64;            // H direction
        int by  = (rem >> 6) * 64;            // D direction
        const float* src = z ? Wr1 : Wb1;
        const size_t moff = (size_t)z * H_DIM * D_IN;
        const int c4 = (t & 15) * 4;
        const int r0 = (t >> 4) * 4;
#pragma unroll
        for (int rr = 0; rr < 4; ++rr) {
            int r = r0 + rr;
            float4 v = *(const float4*)(src + (size_t)(by + r) * H_DIM + bx + c4);
            tile[r][c4 + 0] = v.x; tile[r][c4 + 1] = v.y;
            tile[r][c4 + 2] = v.z; tile[r][c4 + 3] = v.w;
        }
        __syncthreads();
#pragma unroll
        for (int rr = 0; rr < 4; ++rr) {
            int c = r0 + rr;
            ushort4 h, l;
            float f0 = tile[c4 + 0][c], f1 = tile[c4 + 1][c];
            float f2 = tile[c4 + 2][c], f3 = tile[c4 + 3][c];
            h.x = f2bf_rne(f0); l.x = f2bf_rne(f0 - b2f(h.x));
            h.y = f2bf_rne(f1); l.y = f2bf_rne(f1 - b2f(h.y));
            h.z = f2bf_rne(f2); l.z = f2bf_rne(f2 - b2f(h.z));
            h.w = f2bf_rne(f3); l.w = f2bf_rne(f3 - b2f(h.w));
            size_t o = moff + (size_t)(bx + c) * D_IN + by + c4;
            *(ushort4*)(WThi + o) = h;
            *(ushort4*)(WTlo + o) = l;
        }
    } else {
#pragma unroll
        for (int j = 0; j < 4; ++j)
            logits[(bid - 6144) * 1024 + j * 256 + t] = 0.f;   // 32 blocks x 1024 = 32768
    }
}

// ------------- fused split-f32 GEMM + relu + (.)@W2 reduction -------------
// ROUND-0 STRUCTURE VERBATIM (proven: 622 us, 0 bank conflicts, MfmaUtil 62%):
// BK=32, 64B LDS rows, XOR swizzle phys16Bchunk = logical ^ ((row>>1)&3), same staging,
// single-buffer, STAGE -> sync -> compute -> sync, 4 waves, 64m x 128n wave tile,
// 48 KB LDS, __launch_bounds__(256,2) -> 2 blocks/CU.
// ONE change: MFMA 16x16x32 -> 32x32x16 (measured pipe 2495 vs 2176 TF, -13% pipe time).
// Operand layout 32x32: row = lane&31, k-half = lane>>5 (8 contiguous k each);
// BK=32 -> 2 k-steps per chunk, logical 16B chunk = ks*2 + (lane>>5).
// Per 16-lane phase: 16 consecutive rows x 1 logical chunk, XOR spreads rows 0..7 over
// all 8 bank granule groups -> same conflict-free structure as round 0's proven read.
// C/D layout (col=lane&31, row=(reg&3)+8*(reg>>2)+4*(lane>>5)) verified by round-3 pass.
__global__ void __launch_bounds__(256, 2)
gemm_fused3(const unsigned short* __restrict__ Xhi, const unsigned short* __restrict__ Xlo,
            const unsigned short* __restrict__ WThi, const unsigned short* __restrict__ WTlo,
            const float* __restrict__ b1b, const float* __restrict__ b1r,
            const float* __restrict__ w2b, const float* __restrict__ w2r,
            float* __restrict__ logits)              // [2][B][T] f32, atomically accumulated
{
    __shared__ __align__(16) unsigned short Ahi_s[128 * 32];   // 8 KB
    __shared__ __align__(16) unsigned short Alo_s[128 * 32];   // 8 KB
    __shared__ __align__(16) unsigned short Bhi_s[256 * 32];   // 16 KB
    __shared__ __align__(16) unsigned short Blo_s[256 * 32];   // 16 KB

    const int t    = threadIdx.x;
    const int wave = t >> 6;
    const int lane = t & 63;
    const int l31  = lane & 31;
    const int h1   = lane >> 5;              // k-half within a 16-k step
    const int wm   = (wave & 1) * 64;        // wave tile 64m x 128n
    const int wn   = (wave >> 1) * 128;

    const int mat = blockIdx.z;
    const int n0  = blockIdx.x * 256;
    const int m0  = blockIdx.y * 128;

    const size_t aoff = (size_t)m0 * D_IN;
    const size_t boff = (size_t)mat * H_DIM * D_IN + (size_t)n0 * D_IN;
    const unsigned short* Ah = Xhi + aoff;
    const unsigned short* Al = Xlo + aoff;
    const unsigned short* Bh = WThi + boff;
    const unsigned short* Bl = WTlo + boff;
    const float* b1 = mat ? b1r : b1b;
    const float* w2 = mat ? w2r : w2b;
    float* out = logits + mat * M_ROWS;

    // staging (BK=32): thread t fills phys chunk (t&3) of row (t>>2)+i*64.
    // Source global chunk = (t&3) ^ ((row>>1)&3) = (t&3) ^ ((t>>3)&3).  [round-0 verbatim]
    const int srow = t >> 2;
    const int scol = (((t & 3) ^ ((t >> 3) & 3)) * 8);

    // fragment read offsets (loop-invariant), ushort units; row stride 32 ushorts (64B).
    // afo[i][ks]: A row = wm + i*32 + l31, logical chunk = ks*2 + h1, XOR by (row>>1)&3.
    int afo[2][2], bfo[4][2];
#pragma unroll
    for (int i = 0; i < 2; ++i) {
        int row = wm + i * 32 + l31;
#pragma unroll
        for (int ks = 0; ks < 2; ++ks)
            afo[i][ks] = row * 32 + (((ks * 2 + h1) ^ ((row >> 1) & 3)) * 8);
    }
#pragma unroll
    for (int j = 0; j < 4; ++j) {
        int row = wn + j * 32 + l31;
#pragma unroll
        for (int ks = 0; ks < 2; ++ks)
            bfo[j][ks] = row * 32 + (((ks * 2 + h1) ^ ((row >> 1) & 3)) * 8);
    }

    f32x16 acc[2][4] = {};

#pragma unroll 1
    for (int kt = 0; kt < D_IN / 32; ++kt) {
        const int k0 = kt * 32;
#pragma unroll
        for (int i = 0; i < 2; ++i)
            load_lds16(Ah + (size_t)(i * 64 + srow) * D_IN + k0 + scol, Ahi_s + i * 2048 + wave * 512);
#pragma unroll
        for (int i = 0; i < 2; ++i)
            load_lds16(Al + (size_t)(i * 64 + srow) * D_IN + k0 + scol, Alo_s + i * 2048 + wave * 512);
#pragma unroll
        for (int i = 0; i < 4; ++i)
            load_lds16(Bh + (size_t)(i * 64 + srow) * D_IN + k0 + scol, Bhi_s + i * 2048 + wave * 512);
#pragma unroll
        for (int i = 0; i < 4; ++i)
            load_lds16(Bl + (size_t)(i * 64 + srow) * D_IN + k0 + scol, Blo_s + i * 2048 + wave * 512);
        __syncthreads();

        // all fragment loads up front; compiler issues fine-grained lgkmcnt per MFMA set
        bf16x8 afh[2][2], afl[2][2], bfh[4][2], bfl[4][2];
#pragma unroll
        for (int i = 0; i < 2; ++i)
#pragma unroll
            for (int ks = 0; ks < 2; ++ks) {
                afh[i][ks] = *(const bf16x8*)(Ahi_s + afo[i][ks]);
                afl[i][ks] = *(const bf16x8*)(Alo_s + afo[i][ks]);
            }
#pragma unroll
        for (int j = 0; j < 4; ++j)
#pragma unroll
            for (int ks = 0; ks < 2; ++ks) {
                bfh[j][ks] = *(const bf16x8*)(Bhi_s + bfo[j][ks]);
                bfl[j][ks] = *(const bf16x8*)(Blo_s + bfo[j][ks]);
            }
#pragma unroll
        for (int i = 0; i < 2; ++i)
#pragma unroll
            for (int j = 0; j < 4; ++j)
#pragma unroll
                for (int ks = 0; ks < 2; ++ks)
                    acc[i][j] = __builtin_amdgcn_mfma_f32_32x32x16_bf16(afh[i][ks], bfh[j][ks], acc[i][j], 0, 0, 0);
#pragma unroll
        for (int i = 0; i < 2; ++i)
#pragma unroll
            for (int j = 0; j < 4; ++j)
#pragma unroll
                for (int ks = 0; ks < 2; ++ks)
                    acc[i][j] = __builtin_amdgcn_mfma_f32_32x32x16_bf16(afl[i][ks], bfh[j][ks], acc[i][j], 0, 0, 0);
#pragma unroll
        for (int i = 0; i < 2; ++i)
#pragma unroll
            for (int j = 0; j < 4; ++j)
#pragma unroll
                for (int ks = 0; ks < 2; ++ks)
                    acc[i][j] = __builtin_amdgcn_mfma_f32_32x32x16_bf16(afh[i][ks], bfl[j][ks], acc[i][j], 0, 0, 0);
        __syncthreads();
    }

    // epilogue: relu(C + b1)*w2, reduce over this tile's n, accumulate to logits.
    // 32x32 C/D layout: col = lane&31, row = (reg&3) + 8*(reg>>2) + 4*(lane>>5).
    float b1v[4], w2v[4];
#pragma unroll
    for (int j = 0; j < 4; ++j) {
        int n = n0 + wn + j * 32 + l31;
        b1v[j] = b1[n];
        w2v[j] = w2[n];
    }
#pragma unroll
    for (int i = 0; i < 2; ++i) {
#pragma unroll
        for (int r = 0; r < 16; ++r) {
            float s = 0.f;
#pragma unroll
            for (int j = 0; j < 4; ++j) {
                float h = acc[i][j][r] + b1v[j];
                s += fmaxf(h, 0.f) * w2v[j];
            }
            s += __shfl_xor(s, 1, 64);
            s += __shfl_xor(s, 2, 64);
            s += __shfl_xor(s, 4, 64);
            s += __shfl_xor(s, 8, 64);
            s += __shfl_xor(s, 16, 64);
            if (l31 == 0) {
                int m = m0 + wm + i * 32 + (r & 3) + 8 * (r >> 2) + 4 * h1;
                atomicAdd(&out[(m & (BATCH - 1)) * T_STEPS + (m >> 2)], s);  // -> [b][t]
            }
        }
    }
}

// ------------- finish: soft output (blocks 0..63) + serial LIF scan (block 64) -------------
// Scan is a 4096-step serial chain; loads are L2-latency-bound if issued in-chain.
// Fix: 16-step register prefetch ring (load chunk c+1 before processing chunk c;
// ~250 cyc of chain work hides the ~200 cyc L2 latency). x+bb2 / rl>0 computed off-chain.
__global__ void __launch_bounds__(256)
finish(const float* __restrict__ logits,
       const float* __restrict__ bb2p, const float* __restrict__ br2p,
       float* __restrict__ out)
{
    if (blockIdx.x < 64) {
        int i = blockIdx.x * 256 + threadIdx.x;
        out[i] = logits[i] + bb2p[0];                // soft = boundary logits [b][t] + bb2
        return;
    }
    int b = threadIdx.x;
    if (b >= BATCH) return;
    const float bb2 = bb2p[0];
    const float br2 = br2p[0];
    const float* xb = logits + b * T_STEPS;          // boundary logits, [b][t]
    const float* xr = logits + M_ROWS + b * T_STEPS; // reset logits
    float* hb = out + M_ROWS + b * T_STEPS;

    float4 cx[4], cr[4], nx[4] = {}, nr[4] = {};
#pragma unroll
    for (int q = 0; q < 4; ++q) {
        cx[q] = *(const float4*)(xb + q * 4);
        cr[q] = *(const float4*)(xr + q * 4);
    }

    float v = 0.f;
    for (int t0 = 0; t0 < T_STEPS; t0 += 16) {
        if (t0 + 16 < T_STEPS) {
#pragma unroll
            for (int q = 0; q < 4; ++q) {
                nx[q] = *(const float4*)(xb + t0 + 16 + q * 4);
                nr[q] = *(const float4*)(xr + t0 + 16 + q * 4);
            }
        }
#pragma unroll
        for (int q = 0; q < 4; ++q) {
            // off-chain precompute (same ops as before, just hoisted)
            float xs[4] = { cx[q].x + bb2, cx[q].y + bb2, cx[q].z + bb2, cx[q].w + bb2 };
            bool  rm[4] = { cr[q].x + br2 > 0.f, cr[q].y + br2 > 0.f,
                            cr[q].z + br2 > 0.f, cr[q].w + br2 > 0.f };
            float4 sv;
#pragma unroll
            for (int u = 0; u < 4; ++u) {
                v = v + (xs[u] - v) * 0.5f;          // bit-identical to reference step
                bool spike = (v >= 1.0f);
                ((float*)&sv)[u] = spike ? 1.0f : 0.0f;
                v = (spike || rm[u]) ? 0.f : v;
            }
            *(float4*)(hb + t0 + q * 4) = sv;
        }
#pragma unroll
        for (int q = 0; q < 4; ++q) { cx[q] = nx[q]; cr[q] = nr[q]; }
    }
}

extern "C" void kernel_launch(void* const* d_in, const int* in_sizes, int n_in,
                              void* d_out, int out_size, void* d_ws, size_t ws_size,
                              hipStream_t stream) {
    // dict order (confirmed): hidden, Wb1, bb1, Wb2, bb2, Wr1, br1, Wr2, br2
    const float* hidden = (const float*)d_in[0];   // [T,B,D] f32
    const float* Wb1    = (const float*)d_in[1];   // [D,H]
    const float* bb1    = (const float*)d_in[2];   // [H]
    const float* Wb2    = (const float*)d_in[3];   // [H,1]
    const float* bb2    = (const float*)d_in[4];   // [1]
    const float* Wr1    = (const float*)d_in[5];
    const float* br1    = (const float*)d_in[6];
    const float* Wr2    = (const float*)d_in[7];
    const float* br2    = (const float*)d_in[8];
    float* out = (float*)d_out;                    // f32: [soft B*T][hard B*T]

    // ws layout (96.13 MB): Xhi 32MB | Xlo 32MB | WThi 16MB | WTlo 16MB | logits 128KB
    unsigned short* Xhi  = (unsigned short*)d_ws;
    unsigned short* Xlo  = Xhi  + (size_t)M_ROWS * D_IN;
    unsigned short* WThi = Xlo  + (size_t)M_ROWS * D_IN;
    unsigned short* WTlo = WThi + (size_t)2 * H_DIM * D_IN;
    float* logits = (float*)(WTlo + (size_t)2 * H_DIM * D_IN);

    prep<<<dim3(6176), 256, 0, stream>>>(hidden, Wb1, Wr1, Xhi, Xlo, WThi, WTlo, logits);
    gemm_fused3<<<dim3(H_DIM / 256, M_ROWS / 128, 2), 256, 0, stream>>>(
        Xhi, Xlo, WThi, WTlo, bb1, br1, Wb2, Wr2, logits);
    finish<<<dim3(65), 256, 0, stream>>>(logits, bb2, br2, out);
}

// Round 5
// 1039.998 us; speedup vs baseline: 1.1599x; 1.0278x over previous
//
#include <hip/hip_runtime.h>
#include <hip/hip_bf16.h>
#include <stdint.h>

// Problem constants: [T,B,D]=[4096,4,1024], H=4096. f32 inputs, f32 outputs.
// Outputs: soft [B,T] f32 at out[0..16384), hard [B,T] f32 at out[16384..32768).
#define T_STEPS 4096
#define BATCH   4
#define D_IN    1024
#define H_DIM   4096
#define M_ROWS  (T_STEPS * BATCH)

typedef __attribute__((ext_vector_type(8))) short bf16x8;
typedef __attribute__((ext_vector_type(4))) float f32x4;

__device__ __forceinline__ float b2f(unsigned short u) {
    union { unsigned int i; float f; } x; x.i = ((unsigned int)u) << 16; return x.f;
}
__device__ __forceinline__ unsigned short f2bf_rne(float f) {
    union { float f; unsigned int u; } v; v.f = f;
    return (unsigned short)((v.u + 0x7FFFu + ((v.u >> 16) & 1u)) >> 16);
}

__device__ __forceinline__ void load_lds16(const unsigned short* g, unsigned short* l) {
    __builtin_amdgcn_global_load_lds(
        (const __attribute__((address_space(1))) void*)g,
        (__attribute__((address_space(3))) void*)l, 16, 0, 0);
}

// ---------------- prep: split X (fat blocks) + split/transpose W + zero logits ----------------
// blocks [0,4096): split_x (4 float4/thread) | [4096,6144): split_w | [6144,6176): zero logits
__global__ void __launch_bounds__(256)
prep(const float* __restrict__ hidden,
     const float* __restrict__ Wb1, const float* __restrict__ Wr1,
     unsigned short* __restrict__ Xhi, unsigned short* __restrict__ Xlo,
     unsigned short* __restrict__ WThi, unsigned short* __restrict__ WTlo,
     float* __restrict__ logits)
{
    __shared__ float tile[64][65];
    const int bid = blockIdx.x;
    const int t = threadIdx.x;

    if (bid < 4096) {
        // split hidden f32 -> (hi, lo) bf16, same layout; 4 coalesced float4 per thread
#pragma unroll
        for (int j = 0; j < 4; ++j) {
            int i = bid * 1024 + j * 256 + t;
            float4 x = ((const float4*)hidden)[i];
            ushort4 h, l;
            h.x = f2bf_rne(x.x); l.x = f2bf_rne(x.x - b2f(h.x));
            h.y = f2bf_rne(x.y); l.y = f2bf_rne(x.y - b2f(h.y));
            h.z = f2bf_rne(x.z); l.z = f2bf_rne(x.z - b2f(h.z));
            h.w = f2bf_rne(x.w); l.w = f2bf_rne(x.w - b2f(h.w));
            ((ushort4*)Xhi)[i] = h;
            ((ushort4*)Xlo)[i] = l;
        }
    } else if (bid < 6144) {
        // transpose+split W [D][H] -> WT [H][D] for both matrices
        int wb  = bid - 4096;
        int z   = wb >> 10;                   // 0=boundary, 1=reset
        int rem = wb & 1023;
        int bx  = (rem & 63) * 64;            // H direction
        int by  = (rem >> 6) * 64;            // D direction
        const float* src = z ? Wr1 : Wb1;
        const size_t moff = (size_t)z * H_DIM * D_IN;
        const int c4 = (t & 15) * 4;
        const int r0 = (t >> 4) * 4;
#pragma unroll
        for (int rr = 0; rr < 4; ++rr) {
            int r = r0 + rr;
            float4 v = *(const float4*)(src + (size_t)(by + r) * H_DIM + bx + c4);
            tile[r][c4 + 0] = v.x; tile[r][c4 + 1] = v.y;
            tile[r][c4 + 2] = v.z; tile[r][c4 + 3] = v.w;
        }
        __syncthreads();
#pragma unroll
        for (int rr = 0; rr < 4; ++rr) {
            int c = r0 + rr;
            ushort4 h, l;
            float f0 = tile[c4 + 0][c], f1 = tile[c4 + 1][c];
            float f2 = tile[c4 + 2][c], f3 = tile[c4 + 3][c];
            h.x = f2bf_rne(f0); l.x = f2bf_rne(f0 - b2f(h.x));
            h.y = f2bf_rne(f1); l.y = f2bf_rne(f1 - b2f(h.y));
            h.z = f2bf_rne(f2); l.z = f2bf_rne(f2 - b2f(h.z));
            h.w = f2bf_rne(f3); l.w = f2bf_rne(f3 - b2f(h.w));
            size_t o = moff + (size_t)(bx + c) * D_IN + by + c4;
            *(ushort4*)(WThi + o) = h;
            *(ushort4*)(WTlo + o) = l;
        }
    } else {
#pragma unroll
        for (int j = 0; j < 4; ++j)
            logits[(bid - 6144) * 1024 + j * 256 + t] = 0.f;   // 32 blocks x 1024 = 32768
    }
}

// ------------- fused split-f32 GEMM + relu + (.)@W2 reduction, dbuf @ 2 blocks/CU -------------
// Round-0 geometry verbatim (16x16x32 MFMA, BK=32, 64B rows, proven-0-conflict XOR swizzle,
// 4 waves, 256 thr, same staging/epilogue) with TWO deltas:
//  * BN 256 -> 128: one buffer = 32 KB, so the double buffer is 64 KB -> STILL 2 blocks/CU
//    (round 1's dbuf lost this; m114 inter-block overlap preserved).
//  * double-buffer pipeline: STAGE(S1,kt+1); COMPUTE(S0); sync; STAGE(S0,kt+2); COMPUTE(S1);
//    sync. The auto vmcnt(0) at each barrier now covers loads that had a full compute phase
//    (~470 cyc/SIMD) to land, instead of draining right after issue.
// Wave tile 64m x 64n (4x4 frags, 16x16x32). A and B staged geometry now identical.
__global__ void __launch_bounds__(256, 2)
gemm_fused3(const unsigned short* __restrict__ Xhi, const unsigned short* __restrict__ Xlo,
            const unsigned short* __restrict__ WThi, const unsigned short* __restrict__ WTlo,
            const float* __restrict__ b1b, const float* __restrict__ b1r,
            const float* __restrict__ w2b, const float* __restrict__ w2r,
            float* __restrict__ logits)              // [2][B][T] f32, atomically accumulated
{
    // per-buffer layout (ushort offsets): Ahi [0,4096) | Alo [4096,8192) |
    // Bhi [8192,12288) | Blo [12288,16384). 32 KB per buffer, 64 KB total.
    __shared__ __align__(16) unsigned short S0[16384];
    __shared__ __align__(16) unsigned short S1[16384];

    const int t    = threadIdx.x;
    const int wave = t >> 6;
    const int lane = t & 63;
    const int quad = lane >> 4;
    const int lr   = lane & 15;
    const int wm   = (wave & 1) * 64;        // wave tile 64m x 64n
    const int wn   = (wave >> 1) * 64;

    const int mat = blockIdx.z;
    const int n0  = blockIdx.x * 128;
    const int m0  = blockIdx.y * 128;

    const size_t aoff = (size_t)m0 * D_IN;
    const size_t boff = (size_t)mat * H_DIM * D_IN + (size_t)n0 * D_IN;
    const unsigned short* Ah = Xhi + aoff;
    const unsigned short* Al = Xlo + aoff;
    const unsigned short* Bh = WThi + boff;
    const unsigned short* Bl = WTlo + boff;
    const float* b1 = mat ? b1r : b1b;
    const float* w2 = mat ? w2r : w2b;
    float* out = logits + mat * M_ROWS;

    // staging (BK=32, round-0 verbatim): thread t fills phys chunk (t&3) of row (t>>2)+i*64.
    // Source global chunk = (t&3) ^ ((row>>1)&3) = (t&3) ^ ((t>>3)&3).
    const int srow = t >> 2;
    const int scol = (((t & 3) ^ ((t >> 3) & 3)) * 8);
    const int ldsw = wave * 512;             // ushort offset of this wave's 1KB stripe

#define STAGE(S, kt_)                                                           \
    do {                                                                        \
        const int k0_ = (kt_) * 32;                                             \
        _Pragma("unroll") for (int i = 0; i < 2; ++i)                           \
            load_lds16(Ah + (size_t)(i * 64 + srow) * D_IN + k0_ + scol,        \
                       (S) + i * 2048 + ldsw);                                  \
        _Pragma("unroll") for (int i = 0; i < 2; ++i)                           \
            load_lds16(Al + (size_t)(i * 64 + srow) * D_IN + k0_ + scol,        \
                       (S) + 4096 + i * 2048 + ldsw);                           \
        _Pragma("unroll") for (int i = 0; i < 2; ++i)                           \
            load_lds16(Bh + (size_t)(i * 64 + srow) * D_IN + k0_ + scol,        \
                       (S) + 8192 + i * 2048 + ldsw);                           \
        _Pragma("unroll") for (int i = 0; i < 2; ++i)                           \
            load_lds16(Bl + (size_t)(i * 64 + srow) * D_IN + k0_ + scol,        \
                       (S) + 12288 + i * 2048 + ldsw);                          \
    } while (0)

    // fragment read offsets (loop-invariant); round-0 proven conflict-free swizzle
    int afo[4], bfo[4];
#pragma unroll
    for (int i = 0; i < 4; ++i) {
        int ra = wm + i * 16 + lr;
        afo[i] = ra * 32 + ((quad ^ ((ra >> 1) & 3)) * 8);
        int rb = wn + i * 16 + lr;
        bfo[i] = rb * 32 + ((quad ^ ((rb >> 1) & 3)) * 8);
    }

    f32x4 acc[4][4] = {};

#define COMPUTE(S)                                                              \
    do {                                                                        \
        bf16x8 afh[4], afl[4], bfh[4], bfl[4];                                  \
        _Pragma("unroll") for (int i = 0; i < 4; ++i) {                         \
            afh[i] = *(const bf16x8*)((S) + afo[i]);                            \
            afl[i] = *(const bf16x8*)((S) + 4096 + afo[i]);                     \
            bfh[i] = *(const bf16x8*)((S) + 8192 + bfo[i]);                     \
            bfl[i] = *(const bf16x8*)((S) + 12288 + bfo[i]);                    \
        }                                                                       \
        _Pragma("unroll") for (int i = 0; i < 4; ++i)                           \
        _Pragma("unroll") for (int j = 0; j < 4; ++j)                           \
            acc[i][j] = __builtin_amdgcn_mfma_f32_16x16x32_bf16(afh[i], bfh[j], acc[i][j], 0, 0, 0); \
        _Pragma("unroll") for (int i = 0; i < 4; ++i)                           \
        _Pragma("unroll") for (int j = 0; j < 4; ++j)                           \
            acc[i][j] = __builtin_amdgcn_mfma_f32_16x16x32_bf16(afl[i], bfh[j], acc[i][j], 0, 0, 0); \
        _Pragma("unroll") for (int i = 0; i < 4; ++i)                           \
        _Pragma("unroll") for (int j = 0; j < 4; ++j)                           \
            acc[i][j] = __builtin_amdgcn_mfma_f32_16x16x32_bf16(afh[i], bfl[j], acc[i][j], 0, 0, 0); \
    } while (0)

    STAGE(S0, 0);
    __syncthreads();                          // prologue drain (auto vmcnt(0))

#pragma unroll 1
    for (int kt = 0; kt < D_IN / 32; kt += 2) {
        STAGE(S1, kt + 1);                    // prefetch next chunk into other buffer
        COMPUTE(S0);                          // 48 MFMA cover the stage latency
        __syncthreads();                      // auto vmcnt(0): S1 ready, S0 reads done
        if (kt + 2 < D_IN / 32) STAGE(S0, kt + 2);
        COMPUTE(S1);
        __syncthreads();
    }

    // epilogue: relu(C + b1)*w2, reduce over this tile's n, accumulate to logits
    float b1v[4], w2v[4];
#pragma unroll
    for (int j = 0; j < 4; ++j) {
        int n = n0 + wn + j * 16 + lr;               // C/D col = lane&15
        b1v[j] = b1[n];
        w2v[j] = w2[n];
    }
#pragma unroll
    for (int i = 0; i < 4; ++i) {
#pragma unroll
        for (int r = 0; r < 4; ++r) {
            float s = 0.f;
#pragma unroll
            for (int j = 0; j < 4; ++j) {
                float h = acc[i][j][r] + b1v[j];
                s += fmaxf(h, 0.f) * w2v[j];
            }
            s += __shfl_xor(s, 1, 64);
            s += __shfl_xor(s, 2, 64);
            s += __shfl_xor(s, 4, 64);
            s += __shfl_xor(s, 8, 64);
            if (lr == 0) {
                int m = m0 + wm + i * 16 + quad * 4 + r;   // C/D row = quad*4 + reg
                atomicAdd(&out[(m & (BATCH - 1)) * T_STEPS + (m >> 2)], s);  // -> [b][t]
            }
        }
    }
#undef STAGE
#undef COMPUTE
}

// ------------- finish: soft output (blocks 0..63) + serial LIF scan (block 64) -------------
// Scan is a 4096-step serial chain; loads are L2-latency-bound if issued in-chain.
// Fix: 16-step register prefetch ring (load chunk c+1 before processing chunk c;
// ~250 cyc of chain work hides the ~200 cyc L2 latency). x+bb2 / rl>0 computed off-chain.
__global__ void __launch_bounds__(256)
finish(const float* __restrict__ logits,
       const float* __restrict__ bb2p, const float* __restrict__ br2p,
       float* __restrict__ out)
{
    if (blockIdx.x < 64) {
        int i = blockIdx.x * 256 + threadIdx.x;
        out[i] = logits[i] + bb2p[0];                // soft = boundary logits [b][t] + bb2
        return;
    }
    int b = threadIdx.x;
    if (b >= BATCH) return;
    const float bb2 = bb2p[0];
    const float br2 = br2p[0];
    const float* xb = logits + b * T_STEPS;          // boundary logits, [b][t]
    const float* xr = logits + M_ROWS + b * T_STEPS; // reset logits
    float* hb = out + M_ROWS + b * T_STEPS;

    float4 cx[4], cr[4], nx[4] = {}, nr[4] = {};
#pragma unroll
    for (int q = 0; q < 4; ++q) {
        cx[q] = *(const float4*)(xb + q * 4);
        cr[q] = *(const float4*)(xr + q * 4);
    }

    float v = 0.f;
    for (int t0 = 0; t0 < T_STEPS; t0 += 16) {
        if (t0 + 16 < T_STEPS) {
#pragma unroll
            for (int q = 0; q < 4; ++q) {
                nx[q] = *(const float4*)(xb + t0 + 16 + q * 4);
                nr[q] = *(const float4*)(xr + t0 + 16 + q * 4);
            }
        }
#pragma unroll
        for (int q = 0; q < 4; ++q) {
            // off-chain precompute (same ops as before, just hoisted)
            float xs[4] = { cx[q].x + bb2, cx[q].y + bb2, cx[q].z + bb2, cx[q].w + bb2 };
            bool  rm[4] = { cr[q].x + br2 > 0.f, cr[q].y + br2 > 0.f,
                            cr[q].z + br2 > 0.f, cr[q].w + br2 > 0.f };
            float4 sv;
#pragma unroll
            for (int u = 0; u < 4; ++u) {
                v = v + (xs[u] - v) * 0.5f;          // bit-identical to reference step
                bool spike = (v >= 1.0f);
                ((float*)&sv)[u] = spike ? 1.0f : 0.0f;
                v = (spike || rm[u]) ? 0.f : v;
            }
            *(float4*)(hb + t0 + q * 4) = sv;
        }
#pragma unroll
        for (int q = 0; q < 4; ++q) { cx[q] = nx[q]; cr[q] = nr[q]; }
    }
}

extern "C" void kernel_launch(void* const* d_in, const int* in_sizes, int n_in,
                              void* d_out, int out_size, void* d_ws, size_t ws_size,
                              hipStream_t stream) {
    // dict order (confirmed): hidden, Wb1, bb1, Wb2, bb2, Wr1, br1, Wr2, br2
    const float* hidden = (const float*)d_in[0];   // [T,B,D] f32
    const float* Wb1    = (const float*)d_in[1];   // [D,H]
    const float* bb1    = (const float*)d_in[2];   // [H]
    const float* Wb2    = (const float*)d_in[3];   // [H,1]
    const float* bb2    = (const float*)d_in[4];   // [1]
    const float* Wr1    = (const float*)d_in[5];
    const float* br1    = (const float*)d_in[6];
    const float* Wr2    = (const float*)d_in[7];
    const float* br2    = (const float*)d_in[8];
    float* out = (float*)d_out;                    // f32: [soft B*T][hard B*T]

    // ws layout (96.13 MB): Xhi 32MB | Xlo 32MB | WThi 16MB | WTlo 16MB | logits 128KB
    unsigned short* Xhi  = (unsigned short*)d_ws;
    unsigned short* Xlo  = Xhi  + (size_t)M_ROWS * D_IN;
    unsigned short* WThi = Xlo  + (size_t)M_ROWS * D_IN;
    unsigned short* WTlo = WThi + (size_t)2 * H_DIM * D_IN;
    float* logits = (float*)(WTlo + (size_t)2 * H_DIM * D_IN);

    prep<<<dim3(6176), 256, 0, stream>>>(hidden, Wb1, Wr1, Xhi, Xlo, WThi, WTlo, logits);
    gemm_fused3<<<dim3(H_DIM / 128, M_ROWS / 128, 2), 256, 0, stream>>>(
        Xhi, Xlo, WThi, WTlo, bb1, br1, Wb2, Wr2, logits);
    finish<<<dim3(65), 256, 0, stream>>>(logits, bb2, br2, out);
}